// Round 12
// baseline (413.648 us; speedup 1.0000x reference)
//
#include <hip/hip_runtime.h>
#include <math.h>

// Problem constants
#define BATCH 2
#define SEQ   2048
#define DIM   2048
#define NH    16
#define HD    128
#define EPS   1e-6f

typedef _Float16 f16x8 __attribute__((ext_vector_type(8)));
typedef _Float16 f16x4 __attribute__((ext_vector_type(4)));
typedef _Float16 f16x2 __attribute__((ext_vector_type(2)));
typedef float    f32x4 __attribute__((ext_vector_type(4)));

#define MFMA_F16 __builtin_amdgcn_mfma_f32_16x16x32_f16

// ---------------------------------------------------------------------------
// One conversion kernel for all three fp32->fp16 inputs (x, Wqkv, Wproj).
// ---------------------------------------------------------------------------
__global__ __launch_bounds__(256) void cvt_all(
    const float* __restrict__ x, const float* __restrict__ wqkv,
    const float* __restrict__ wproj, _Float16* __restrict__ x16,
    _Float16* __restrict__ wh, _Float16* __restrict__ wph) {
  int bid = blockIdx.x;
  const float* in;
  _Float16* out;
  int i;
  if (bid < 8192)       { in = x;     out = x16; i = bid; }
  else if (bid < 20480) { in = wqkv;  out = wh;  i = bid - 8192; }
  else                  { in = wproj; out = wph; i = bid - 20480; }
  int j = i * 256 + threadIdx.x;
  float4 v = ((const float4*)in)[j];
  f16x4 o;
  o[0] = (_Float16)v.x; o[1] = (_Float16)v.y;
  o[2] = (_Float16)v.z; o[3] = (_Float16)v.w;
  ((f16x4*)out)[j] = o;
}

// Shared main-loop macros for both GEMMs (round-9 proven structure:
// BM=128 BN=256 BK=64, 8 waves 2x4, per-wave 64x64, cross-tile register
// pipelining, XOR-8 swizzle on 128B rows, zero bank conflicts).
#define GEMM_PREAMBLE()                                                        \
  const int t = threadIdx.x;                                                   \
  const int w = t >> 6, lane = t & 63;                                         \
  const int bm = blockIdx.y * 128, bn = blockIdx.x * 256;                      \
  const int wr = (w >> 2) * 64;                                                \
  const int wc = (w & 3) * 64;                                                 \
  const int quad = lane >> 4, c15 = lane & 15;                                 \
  const _Float16* baseA = Ag + (size_t)bm * K;                                 \
  const _Float16* baseB = Bg + (size_t)bn * K;                                 \
  const int lrow = lane >> 3;                                                  \
  const int lswz = ((lane & 7) ^ lrow) * 8;                                    \
  const int col0 = ((0 + quad) ^ (c15 & 7)) * 8;                               \
  const int col1 = ((4 + quad) ^ (c15 & 7)) * 8;                               \
  f32x4 acc[4][4] = {};                                                        \
  f16x8 a0[4], b0[4], a1[4], b1[4];

#define STAGE_TILE(buf, kofs)                                                  \
  {                                                                            \
    _Pragma("unroll")                                                          \
    for (int e = 0; e < 6; ++e) {                                              \
      int c = w * 6 + e;                                                       \
      int rl = c * 8 + lrow;                                                   \
      const _Float16* g = (rl < 128) ? (baseA + (size_t)rl * K)                \
                                     : (baseB + (size_t)(rl - 128) * K);       \
      __builtin_amdgcn_global_load_lds(                                        \
          (const __attribute__((address_space(1))) unsigned int*)(g + (kofs) + lswz), \
          (__attribute__((address_space(3))) unsigned int*)(&smem[buf][c * 8][0]),    \
          16, 0, 0);                                                           \
    }                                                                          \
  }

#define RD(dstA, dstB, colv, buf)                                              \
  _Pragma("unroll")                                                            \
  for (int m2 = 0; m2 < 4; ++m2)                                               \
    dstA[m2] = *(const f16x8*)(&smem[buf][wr + m2 * 16 + c15][colv]);          \
  _Pragma("unroll")                                                            \
  for (int n2 = 0; n2 < 4; ++n2)                                               \
    dstB[n2] = *(const f16x8*)(&smem[buf][128 + wc + n2 * 16 + c15][colv]);

#define MM(af, bf)                                                             \
  _Pragma("unroll")                                                            \
  for (int m2 = 0; m2 < 4; ++m2)                                               \
    _Pragma("unroll")                                                          \
    for (int n2 = 0; n2 < 4; ++n2)                                             \
      acc[m2][n2] = MFMA_F16(af[m2], bf[n2], acc[m2][n2], 0, 0, 0);

#define SB() __builtin_amdgcn_sched_barrier(0);

#define GEMM_MAINLOOP()                                                        \
  STAGE_TILE(0, 0)                                                             \
  asm volatile("s_waitcnt vmcnt(0)" ::: "memory");                             \
  SB();                                                                        \
  __builtin_amdgcn_s_barrier();                                                \
  SB();                                                                        \
  STAGE_TILE(1, 64)                                                            \
  RD(a0, b0, col0, 0);                                                         \
  const int NT = K >> 6;                                                       \
  for (int tt = 0; tt < NT; ++tt) {                                            \
    const int buf = tt & 1;                                                    \
    RD(a1, b1, col1, buf);                                                     \
    __builtin_amdgcn_s_setprio(1);                                             \
    MM(a0, b0);                                                                \
    __builtin_amdgcn_s_setprio(0);                                             \
    asm volatile("s_waitcnt lgkmcnt(0)" ::: "memory");                         \
    asm volatile("s_waitcnt vmcnt(0)" ::: "memory");                           \
    SB();                                                                      \
    __builtin_amdgcn_s_barrier();                                              \
    SB();                                                                      \
    if (tt + 2 < NT) { STAGE_TILE(buf, (tt + 2) * 64) }                        \
    if (tt + 1 < NT) { RD(a0, b0, col0, 1 - buf); }                            \
    __builtin_amdgcn_s_setprio(1);                                             \
    MM(a1, b1);                                                                \
    __builtin_amdgcn_s_setprio(0);                                             \
  }

// ---------------------------------------------------------------------------
// QKV GEMM with FUSED rmsnorm+rope+V-transpose epilogue (round-12).
// A block's 256 cols = exactly 2 complete heads of one region (q/k/v) and
// its 128 rows = 128 s of one batch -> whole head vectors live in acc.
//  q/k: rmsnorm (n-sum -> c15 butterfly -> 2KB LDS partner-wave exchange),
//       rope (pairs = adjacent c15 lanes, shfl_xor(1)), write Q16/K16
//       [b,h,s,d] as packed f16x2 from fp32 acc (better precision than the
//       old qkv16 fp16 round-trip).
//  v:   LDS transpose (reuse 96KB smem, [128][132] pad) -> coalesced Vt
//       [b,h,d,s] writes.
// Eliminates the rope_vtrans kernel + 100 MB of qkv16 traffic.
// ---------------------------------------------------------------------------
__global__ __launch_bounds__(512, 2) void gemm_qkv(
    const _Float16* __restrict__ Ag, const _Float16* __restrict__ Bg,
    const float* __restrict__ cosb, const float* __restrict__ sinb,
    _Float16* __restrict__ Qg, _Float16* __restrict__ Kg,
    _Float16* __restrict__ Vt, int K) {
  __shared__ __align__(16) _Float16 smem[2][384][64];
  GEMM_PREAMBLE()
  GEMM_MAINLOOP()

  // ---- fused epilogue ----
  const int region = bn >> 11;          // 0=q, 1=k, 2=v
  const int b = bm >> 11;
  const int s0 = bm & (SEQ - 1);

  if (region < 2) {
    float* LDSf = (float*)smem;
    float ps[4][4];
    #pragma unroll
    for (int m2 = 0; m2 < 4; ++m2)
      #pragma unroll
      for (int r = 0; r < 4; ++r) {
        float p = 0.f;
        #pragma unroll
        for (int n = 0; n < 4; ++n) p += acc[m2][n][r] * acc[m2][n][r];
        #pragma unroll
        for (int off = 8; off >= 1; off >>= 1) p += __shfl_xor(p, off, 64);
        ps[m2][r] = p;
      }
    __syncthreads();
    if (c15 == 0) {
      #pragma unroll
      for (int m2 = 0; m2 < 4; ++m2)
        #pragma unroll
        for (int r = 0; r < 4; ++r)
          LDSf[w * 64 + 16 * m2 + quad * 4 + r] = ps[m2][r];
    }
    __syncthreads();
    _Float16* dst = (region == 0) ? Qg : Kg;
    const int h = ((bn & (2 * DIM - 1)) >> 7) & 15;  // head base within region
    const int hh = h + (wc >> 7);
    const int dbase = wc & 64;
    #pragma unroll
    for (int m2 = 0; m2 < 4; ++m2)
      #pragma unroll
      for (int r = 0; r < 4; ++r) {
        float tot = ps[m2][r] + LDSf[(w ^ 1) * 64 + 16 * m2 + quad * 4 + r];
        float rsq = rsqrtf(tot * (1.0f / HD) + EPS);
        int s = s0 + wr + 16 * m2 + quad * 4 + r;
        #pragma unroll
        for (int n = 0; n < 4; ++n) {
          int dh = dbase + 16 * n + c15;
          float v = acc[m2][n][r] * rsq;
          float vp = __shfl_xor(v, 1, 64);
          float cs = cosb[s * HD + (dh & ~1)];
          float sn = sinb[s * HD + (dh & ~1)];
          float y = ((c15 & 1) == 0) ? (v * cs - vp * sn) : (vp * sn + v * cs);
          float yp = __shfl_xor(y, 1, 64);
          if ((c15 & 1) == 0) {
            f16x2 o2;
            o2[0] = (_Float16)y; o2[1] = (_Float16)yp;
            *(f16x2*)(dst + ((size_t)(b * NH + hh) * SEQ + s) * HD + dh) = o2;
          }
        }
      }
  } else {
    _Float16* Lh = (_Float16*)smem;     // [128][132] pad-4
    const int hv0 = ((bn & (2 * DIM - 1)) >> 7) & 15;
    const int d_out = t & 127;
    const int sq0 = (t >> 7) * 32;
    #pragma unroll
    for (int half = 0; half < 2; ++half) {
      __syncthreads();
      if ((wc >> 7) == half) {
        #pragma unroll
        for (int m2 = 0; m2 < 4; ++m2)
          #pragma unroll
          for (int n = 0; n < 4; ++n)
            #pragma unroll
            for (int r = 0; r < 4; ++r)
              Lh[(wr + 16 * m2 + quad * 4 + r) * 132 + (wc & 64) + 16 * n + c15] =
                  (_Float16)acc[m2][n][r];
      }
      __syncthreads();
      size_t dst = ((size_t)(b * NH + hv0 + half) * HD + d_out) * SEQ + s0 + sq0;
      #pragma unroll
      for (int j = 0; j < 8; ++j) {
        f16x4 o;
        o[0] = Lh[(sq0 + 4 * j + 0) * 132 + d_out];
        o[1] = Lh[(sq0 + 4 * j + 1) * 132 + d_out];
        o[2] = Lh[(sq0 + 4 * j + 2) * 132 + d_out];
        o[3] = Lh[(sq0 + 4 * j + 3) * 132 + d_out];
        *(f16x4*)(Vt + dst + 4 * j) = o;
      }
    }
  }
}

// ---------------------------------------------------------------------------
// Plain single-pass GEMM for the output projection (fp32 out).
// ---------------------------------------------------------------------------
__global__ __launch_bounds__(512, 2) void gemm_proj(
    const _Float16* __restrict__ Ag, const _Float16* __restrict__ Bg,
    float* __restrict__ C, int N, int K) {
  __shared__ __align__(16) _Float16 smem[2][384][64];
  GEMM_PREAMBLE()
  GEMM_MAINLOOP()
  #pragma unroll
  for (int m2 = 0; m2 < 4; ++m2)
    #pragma unroll
    for (int n2 = 0; n2 < 4; ++n2) {
      int col = bn + wc + 16 * n2 + c15;
      #pragma unroll
      for (int r = 0; r < 4; ++r) {
        int row = bm + wr + 16 * m2 + quad * 4 + r;
        C[(size_t)row * N + col] = acc[m2][n2][r];
      }
    }
}

// ---------------------------------------------------------------------------
// fp16 MFMA flash attention, fixed-max softmax (round-8/9 state, unchanged).
// LDS f16 units: K[2] [0,8192)  Vt[2] [8192,16384)  P [16384,21504)
// per wave [32][40].  Q staging reuses [0,16384).
// ---------------------------------------------------------------------------
#define QT 128
#define KC 32

__global__ __launch_bounds__(256, 2) void flash_f16(
    const _Float16* __restrict__ Qg, const _Float16* __restrict__ Kg,
    const _Float16* __restrict__ Vtg, _Float16* __restrict__ Og) {
  __shared__ __align__(16) _Float16 sm[21504];

  const int t = threadIdx.x, w = t >> 6, lane = t & 63;
  const int quad = lane >> 4, c15 = lane & 15;
  const int bid = blockIdx.x;
  const int grp = (bid & 7) * 4 + ((bid >> 3) >> 4);   // 0..31 = b*NH+h
  const int qi  = (bid >> 3) & 15;
  const int bh = grp;
  const int hy = grp & (NH - 1), bz = grp >> 4;
  const int q0 = qi * QT;
  const int wr = w * 32;

  // ---- stage Q [128][128] f16 once; fragments -> registers ----
  {
    const _Float16* qsrc = Qg + ((size_t)bh * SEQ + q0) * HD;
    #pragma unroll
    for (int p = 0; p < 8; ++p) {
      int ci = p * 256 + t;
      int r = ci >> 4, c8 = (ci & 15) ^ (r & 15);
      __builtin_amdgcn_global_load_lds(
          (const __attribute__((address_space(1))) unsigned int*)(qsrc + (size_t)r * HD + c8 * 8),
          (__attribute__((address_space(3))) unsigned int*)(sm + ci * 8), 16, 0, 0);
    }
  }
  __syncthreads();
  f16x8 qf[2][4];  // [mf][ks]
  #pragma unroll
  for (int mf = 0; mf < 2; ++mf)
    #pragma unroll
    for (int ks = 0; ks < 4; ++ks) {
      int m = wr + mf * 16 + c15;
      int c8 = ks * 4 + quad;
      qf[mf][ks] = *(const f16x8*)(sm + (m * 16 + (c8 ^ (m & 15))) * 8);
    }
  asm volatile("s_waitcnt lgkmcnt(0)" ::: "memory");
  __builtin_amdgcn_sched_barrier(0);
  __syncthreads();

  float lrow[8];
  f32x4 oacc[2][8];
  #pragma unroll
  for (int i = 0; i < 8; ++i) lrow[i] = 0.f;
  #pragma unroll
  for (int mf = 0; mf < 2; ++mf)
    #pragma unroll
    for (int nf = 0; nf < 8; ++nf) oacc[mf][nf] = (f32x4){0.f, 0.f, 0.f, 0.f};

  const float sl = 0.12751744f;       // (1/sqrt(128)) * log2(e)
  const float M2 = 16.322231f;        // sqrt(128) * log2(e)
  _Float16* Pw = sm + 16384 + w * 1280;

#define STAGE_KV(buf, kk)                                                     \
  _Pragma("unroll")                                                           \
  for (int e = 0; e < 4; ++e) {                                               \
    int idx = w * 4 + e;                                                      \
    int tile = idx >> 3, p = idx & 7;                                         \
    int ci = p * 64 + lane;                                                   \
    if (tile == 0) {                                                          \
      int r = ci >> 4, c8 = (ci & 15) ^ (r & 15);                             \
      int rp = 2 * (r & 15) + (r >> 4);                                       \
      const _Float16* src = Kg +                                              \
          ((size_t)bh * SEQ + (kk) + rp) * HD + c8 * 8;                       \
      __builtin_amdgcn_global_load_lds(                                       \
          (const __attribute__((address_space(1))) unsigned int*)src,         \
          (__attribute__((address_space(3))) unsigned int*)                   \
              (sm + (buf) * 4096 + ci * 8), 16, 0, 0);                        \
    } else {                                                                  \
      int d = ci >> 2, c8 = (ci & 3) ^ (d & 3);                               \
      const _Float16* src = Vtg + (size_t)bh * HD * SEQ + (size_t)d * SEQ     \
          + (kk) + c8 * 8;                                                    \
      __builtin_amdgcn_global_load_lds(                                       \
          (const __attribute__((address_space(1))) unsigned int*)src,         \
          (__attribute__((address_space(3))) unsigned int*)                   \
              (sm + 8192 + (buf) * 4096 + ci * 8), 16, 0, 0);                 \
    }                                                                         \
  }

  STAGE_KV(0, 0)                       // prologue: chunk 0 -> buf0

  const int NC = SEQ / KC;             // 64
  for (int it = 0; it < NC; ++it) {
    const int cur = it & 1, cb0 = cur * 4096;
    asm volatile("s_waitcnt vmcnt(0)" ::: "memory");
    __builtin_amdgcn_sched_barrier(0);
    __builtin_amdgcn_s_barrier();
    __builtin_amdgcn_sched_barrier(0);
    if (it + 1 < NC) { STAGE_KV(1 - cur, (it + 1) * KC) }

    // ---- S = Q K^T (single pass) ----
    f32x4 accs[2][2] = {};
    #pragma unroll
    for (int nf = 0; nf < 2; ++nf) {
      f16x8 kh[4];
      #pragma unroll
      for (int ks = 0; ks < 4; ++ks) {
        int n = nf * 16 + c15;
        int c8 = ks * 4 + quad;
        kh[ks] = *(const f16x8*)(sm + cb0 + (n * 16 + (c8 ^ (n & 15))) * 8);
      }
      __builtin_amdgcn_s_setprio(1);
      #pragma unroll
      for (int ks = 0; ks < 4; ++ks) {
        accs[0][nf] = MFMA_F16(qf[0][ks], kh[ks], accs[0][nf], 0, 0, 0);
        accs[1][nf] = MFMA_F16(qf[1][ks], kh[ks], accs[1][nf], 0, 0, 0);
      }
      __builtin_amdgcn_s_setprio(0);
    }

    // ---- fixed-shift softmax weights; packed f16x2 P-write ----
    #pragma unroll
    for (int mf = 0; mf < 2; ++mf)
      #pragma unroll
      for (int reg = 0; reg < 4; ++reg) {
        float p0 = exp2f(fmaf(accs[mf][0][reg], sl, -M2));
        float p1 = exp2f(fmaf(accs[mf][1][reg], sl, -M2));
        lrow[mf * 4 + reg] += p0 + p1;
        int prow = mf * 16 + quad * 4 + reg;
        f16x2 pp;
        pp[0] = (_Float16)p0; pp[1] = (_Float16)p1;
        *(f16x2*)(Pw + prow * 40 + 2 * c15) = pp;
      }

    // ---- O += P V ----
    f16x8 pa0 = *(const f16x8*)(Pw + (c15) * 40 + quad * 8);
    f16x8 pa1 = *(const f16x8*)(Pw + (16 + c15) * 40 + quad * 8);
    __builtin_amdgcn_s_setprio(1);
    #pragma unroll
    for (int nf = 0; nf < 8; ++nf) {
      int dd = nf * 16 + c15;
      int slot = (dd * 4 + (quad ^ (dd & 3))) * 8;
      f16x8 vv = *(const f16x8*)(sm + 8192 + cb0 + slot);
      oacc[0][nf] = MFMA_F16(pa0, vv, oacc[0][nf], 0, 0, 0);
      oacc[1][nf] = MFMA_F16(pa1, vv, oacc[1][nf], 0, 0, 0);
    }
    __builtin_amdgcn_s_setprio(0);
  }

  // ---- epilogue: denominator reduce + O write (single fp16) ----
  #pragma unroll
  for (int i = 0; i < 8; ++i) {
    float s = lrow[i];
    #pragma unroll
    for (int off = 8; off >= 1; off >>= 1) s += __shfl_xor(s, off, 64);
    lrow[i] = s;
  }
  #pragma unroll
  for (int mf = 0; mf < 2; ++mf)
    #pragma unroll
    for (int reg = 0; reg < 4; ++reg) {
      float inv = 1.0f / lrow[mf * 4 + reg];
      int row = q0 + wr + mf * 16 + quad * 4 + reg;
      size_t ob = ((size_t)bz * SEQ + row) * DIM + hy * HD + c15;
      #pragma unroll
      for (int nf = 0; nf < 8; ++nf)
        Og[ob + nf * 16] = (_Float16)(oacc[mf][nf][reg] * inv);
    }
#undef STAGE_KV
}

// ---------------------------------------------------------------------------
// Launch (4 kernels).  Workspace (<= 152 MB):
//   ws: Q16 [0,16.7M)  O16 [16.7M,33.5M)  K16 [33.5M,50.3M)  Vt [50.3M,67.1M)
//   R = ws + 100663296:
//     x16 [R,+16.7M)  Wh [R+16.7M,+25.2M)  Wph [R+41.9M,+8.4M)
//   gemm_qkv reads x16/Wh (R-region) and writes Q16/K16/Vt (ws-region):
//   disjoint.  flash reads Q16/K16/Vt, writes O16: disjoint.
// ---------------------------------------------------------------------------
extern "C" void kernel_launch(void* const* d_in, const int* in_sizes, int n_in,
                              void* d_out, int out_size, void* d_ws, size_t ws_size,
                              hipStream_t stream) {
  const float* x     = (const float*)d_in[0];
  const float* cosb  = (const float*)d_in[1];
  const float* sinb  = (const float*)d_in[2];
  const float* Wqkv  = (const float*)d_in[3];
  const float* Wproj = (const float*)d_in[4];
  float* out = (float*)d_out;

  char* ws = (char*)d_ws;
  _Float16* Q16 = (_Float16*)(ws);
  _Float16* O16 = (_Float16*)(ws + 16777216);
  _Float16* K16 = (_Float16*)(ws + 33554432);
  _Float16* Vt  = (_Float16*)(ws + 50331648);
  char* R = ws + 100663296;
  _Float16* x16 = (_Float16*)(R);
  _Float16* Wh  = (_Float16*)(R + 16777216);
  _Float16* Wph = (_Float16*)(R + 41943040);

  cvt_all<<<24576, 256, 0, stream>>>(x, Wqkv, Wproj, x16, Wh, Wph);
  gemm_qkv<<<dim3(24, 32), 512, 0, stream>>>(x16, Wh, cosb, sinb, Q16, K16, Vt, 2048);
  flash_f16<<<512, 256, 0, stream>>>(Q16, K16, Vt, O16);
  gemm_proj<<<dim3(8, 32), 512, 0, stream>>>(O16, Wph, out, 2048, 2048);
}

// Round 13
// 385.265 us; speedup vs baseline: 1.0737x; 1.0737x over previous
//
#include <hip/hip_runtime.h>
#include <math.h>

// Problem constants
#define BATCH 2
#define SEQ   2048
#define DIM   2048
#define NH    16
#define HD    128
#define EPS   1e-6f

typedef _Float16 f16x8 __attribute__((ext_vector_type(8)));
typedef _Float16 f16x4 __attribute__((ext_vector_type(4)));
typedef _Float16 f16x2 __attribute__((ext_vector_type(2)));
typedef float    f32x4 __attribute__((ext_vector_type(4)));

#define MFMA_F16 __builtin_amdgcn_mfma_f32_16x16x32_f16

// ---------------------------------------------------------------------------
// One conversion kernel for all three fp32->fp16 inputs (x, Wqkv, Wproj).
// ---------------------------------------------------------------------------
__global__ __launch_bounds__(256) void cvt_all(
    const float* __restrict__ x, const float* __restrict__ wqkv,
    const float* __restrict__ wproj, _Float16* __restrict__ x16,
    _Float16* __restrict__ wh, _Float16* __restrict__ wph) {
  int bid = blockIdx.x;
  const float* in;
  _Float16* out;
  int i;
  if (bid < 8192)       { in = x;     out = x16; i = bid; }
  else if (bid < 20480) { in = wqkv;  out = wh;  i = bid - 8192; }
  else                  { in = wproj; out = wph; i = bid - 20480; }
  int j = i * 256 + threadIdx.x;
  float4 v = ((const float4*)in)[j];
  f16x4 o;
  o[0] = (_Float16)v.x; o[1] = (_Float16)v.y;
  o[2] = (_Float16)v.z; o[3] = (_Float16)v.w;
  ((f16x4*)out)[j] = o;
}

// ---------------------------------------------------------------------------
// Single-pass fp16 MFMA GEMM, cross-tile register pipelining (round-9/11
// proven: 117us QKV, zero bank conflicts).  Output type templated — QKV
// writes fp16, proj writes fp32.  BM=128 BN=256 BK=64, 8 waves (2x4),
// per-wave 64x64.  LDS 96 KiB, XOR-8 swizzle.
// Round-13: round-12's fused rope epilogue REVERTED (cost +49us: +47MB
// cos/sin fetch, 4B scattered stores, 1-block/CU serial tail).
// ---------------------------------------------------------------------------
template <typename OT>
__global__ __launch_bounds__(512, 2) void gemm_1p(
    const _Float16* __restrict__ Ag, const _Float16* __restrict__ Bg,
    OT* __restrict__ C, int M, int N, int K) {
  // stack rows: [0,128) = A, [128,384) = B; 64 f16 per row.
  __shared__ __align__(16) _Float16 smem[2][384][64];

  const int t = threadIdx.x;
  const int w = t >> 6, lane = t & 63;
  const int bm = blockIdx.y * 128, bn = blockIdx.x * 256;
  const int wr = (w >> 2) * 64;       // wave row offset (2 wave-rows)
  const int wc = (w & 3) * 64;        // wave col offset (4 wave-cols)
  const int quad = lane >> 4, c15 = lane & 15;

  const _Float16* baseA = Ag + (size_t)bm * K;
  const _Float16* baseB = Bg + (size_t)bn * K;

  const int lrow = lane >> 3;
  const int lswz = ((lane & 7) ^ lrow) * 8;    // f16 units

  const int col0 = ((0 + quad) ^ (c15 & 7)) * 8;   // ks=0
  const int col1 = ((4 + quad) ^ (c15 & 7)) * 8;   // ks=1

  f32x4 acc[4][4] = {};
  f16x8 a0[4], b0[4], a1[4], b1[4];   // two fragment sets (ks0 / ks1)

  // 48 staging chunks (A 16, B 32), 6 per wave; chunk = 8 rows x 128B.
#define STAGE_TILE(buf, kofs)                                                  \
  {                                                                            \
    _Pragma("unroll")                                                          \
    for (int e = 0; e < 6; ++e) {                                              \
      int c = w * 6 + e;                                                       \
      int rl = c * 8 + lrow;                                                   \
      const _Float16* g = (rl < 128) ? (baseA + (size_t)rl * K)                \
                                     : (baseB + (size_t)(rl - 128) * K);       \
      __builtin_amdgcn_global_load_lds(                                        \
          (const __attribute__((address_space(1))) unsigned int*)(g + (kofs) + lswz), \
          (__attribute__((address_space(3))) unsigned int*)(&smem[buf][c * 8][0]),    \
          16, 0, 0);                                                           \
    }                                                                          \
  }

  // one half-tile fragment set: 4 A + 4 B ds_read_b128
#define RD(dstA, dstB, colv, buf)                                              \
  _Pragma("unroll")                                                            \
  for (int m2 = 0; m2 < 4; ++m2)                                               \
    dstA[m2] = *(const f16x8*)(&smem[buf][wr + m2 * 16 + c15][colv]);          \
  _Pragma("unroll")                                                            \
  for (int n2 = 0; n2 < 4; ++n2)                                               \
    dstB[n2] = *(const f16x8*)(&smem[buf][128 + wc + n2 * 16 + c15][colv]);

#define MM(af, bf)                                                             \
  _Pragma("unroll")                                                            \
  for (int m2 = 0; m2 < 4; ++m2)                                               \
    _Pragma("unroll")                                                          \
    for (int n2 = 0; n2 < 4; ++n2)                                             \
      acc[m2][n2] = MFMA_F16(af[m2], bf[n2], acc[m2][n2], 0, 0, 0);

#define SB() __builtin_amdgcn_sched_barrier(0);

  // ---- prologue: tile 0 -> buf0; tile 1 in flight; ks0(0) frags loaded ----
  STAGE_TILE(0, 0)
  asm volatile("s_waitcnt vmcnt(0)" ::: "memory");
  SB();
  __builtin_amdgcn_s_barrier();
  SB();
  STAGE_TILE(1, 64)
  RD(a0, b0, col0, 0);

  const int NT = K >> 6;               // 32 K-tiles
  for (int tt = 0; tt < NT; ++tt) {
    const int buf = tt & 1;
    // ---- phase A: read ks1(tt)  ||  MFMA ks0(tt) (read last phase) ----
    RD(a1, b1, col1, buf);
    __builtin_amdgcn_s_setprio(1);
    MM(a0, b0);
    __builtin_amdgcn_s_setprio(0);
    // ---- phase B: barrier; stage tt+2; read ks0(tt+1)  ||  MFMA ks1(tt) ----
    asm volatile("s_waitcnt lgkmcnt(0)" ::: "memory");   // ks1 reads retired
    asm volatile("s_waitcnt vmcnt(0)" ::: "memory");     // tile tt+1 landed
    SB();
    __builtin_amdgcn_s_barrier();
    SB();
    if (tt + 2 < NT) { STAGE_TILE(buf, (tt + 2) * 64) }
    if (tt + 1 < NT) { RD(a0, b0, col0, 1 - buf); }
    __builtin_amdgcn_s_setprio(1);
    MM(a1, b1);
    __builtin_amdgcn_s_setprio(0);
  }

  // C/D layout: col = lane&15, row = (lane>>4)*4 + reg
  #pragma unroll
  for (int m2 = 0; m2 < 4; ++m2)
    #pragma unroll
    for (int n2 = 0; n2 < 4; ++n2) {
      int col = bn + wc + 16 * n2 + c15;
      #pragma unroll
      for (int r = 0; r < 4; ++r) {
        int row = bm + wr + 16 * m2 + quad * 4 + r;
        C[(size_t)row * N + col] = (OT)acc[m2][n2][r];
      }
    }
#undef STAGE_TILE
#undef RD
#undef MM
#undef SB
}

// ---------------------------------------------------------------------------
// Merged RMSNorm+RoPE (blocks [0,4096)) and V-transpose (blocks [4096,5120)).
// qkv fp16 [b,s,3*DIM].  Emits Q,K fp16 [b,h,s,d] and Vt fp16 [b,h,d,s].
// (round-11 proven)
// ---------------------------------------------------------------------------
__global__ __launch_bounds__(256) void rope_vtrans(
    const _Float16* __restrict__ qkv, const float* __restrict__ cosb,
    const float* __restrict__ sinb, _Float16* __restrict__ Qg,
    _Float16* __restrict__ Kg, _Float16* __restrict__ Vt) {
  __shared__ _Float16 L[64 * 132];
  const int bid = blockIdx.x;
  const int t = threadIdx.x;
  if (bid < 4096) {
    // ---- RMSNorm + RoPE on one (b,s) row ----
    const int b = bid >> 11, s = bid & (SEQ - 1);
    const int wave = t >> 6, lane = t & 63;
    const _Float16* base = qkv + (size_t)bid * (3 * DIM);
    const float c  = cosb[s * HD + 2 * lane];
    const float sn = sinb[s * HD + 2 * lane];
    #pragma unroll
    for (int h = wave; h < NH; h += 4) {
      f16x2 qv = *(const f16x2*)(base + h * HD + 2 * lane);
      f16x2 kv = *(const f16x2*)(base + DIM + h * HD + 2 * lane);
      float qx = (float)qv[0], qy = (float)qv[1];
      float kx = (float)kv[0], ky = (float)kv[1];
      float ssq = qx * qx + qy * qy;
      float ssk = kx * kx + ky * ky;
      #pragma unroll
      for (int off = 32; off >= 1; off >>= 1) {
        ssq += __shfl_xor(ssq, off, 64);
        ssk += __shfl_xor(ssk, off, 64);
      }
      float rq = rsqrtf(ssq * (1.0f / HD) + EPS);
      float rk = rsqrtf(ssk * (1.0f / HD) + EPS);
      float q1 = qx * rq, q2 = qy * rq;
      float k1 = kx * rk, k2 = ky * rk;
      float qy1 = q1 * c - q2 * sn, qy2 = q1 * sn + q2 * c;
      float ky1 = k1 * c - k2 * sn, ky2 = k1 * sn + k2 * c;
      size_t o = ((size_t)(b * NH + h) * SEQ + s) * HD + 2 * lane;
      f16x2 qo, ko;
      qo[0] = (_Float16)qy1; qo[1] = (_Float16)qy2;
      ko[0] = (_Float16)ky1; ko[1] = (_Float16)ky2;
      *(f16x2*)(Qg + o) = qo;
      *(f16x2*)(Kg + o) = ko;
    }
  } else {
    // ---- V transpose: [64 s][128 d] fp16 -> Vt [b,h,d,s] ----
    const int vb = bid - 4096;                  // 0..1023
    const int s0 = (vb & 31) * 64, h = (vb >> 5) & 15, b = vb >> 9;
    const _Float16* src =
        qkv + ((size_t)(b * SEQ + s0)) * (3 * DIM) + 2 * DIM + h * HD;
    #pragma unroll
    for (int it = 0; it < 4; ++it) {
      int f = t + it * 256;
      int r = f >> 4, c8 = f & 15;
      f16x8 v = *(const f16x8*)(src + (size_t)r * (3 * DIM) + c8 * 8);
      *(f16x8*)(&L[r * 132 + c8 * 8]) = v;
    }
    __syncthreads();
    const int d = t >> 1, sc = (t & 1) * 32;
    size_t dst = ((size_t)((b * NH + h) * HD + d)) * SEQ + s0 + sc;
    #pragma unroll
    for (int j = 0; j < 8; ++j) {
      f16x4 o;
      o[0] = L[(sc + 4 * j + 0) * 132 + d];
      o[1] = L[(sc + 4 * j + 1) * 132 + d];
      o[2] = L[(sc + 4 * j + 2) * 132 + d];
      o[3] = L[(sc + 4 * j + 3) * 132 + d];
      *(f16x4*)(Vt + dst + j * 4) = o;
    }
  }
}

// ---------------------------------------------------------------------------
// fp16 MFMA flash attention, fixed-max softmax.
// Round-13 change: QT 128 -> 256 with 8 waves (512 thr), grid 512 -> 256
// blocks (1/CU).  Each staged K/V chunk now feeds 256 q-rows instead of
// 128 -> staging traffic AND barrier/drain count per unit work halve.
// Per-wave code identical to the proven round-8 state (each wave still owns
// 32 q-rows).  Prefetch distance stays one full iter (~1800cy >> L2
// latency) so the vmcnt(0) remains pre-drained.
// LDS f16 units: Q-stage [0,32768) one-time; loop reuses K[2] [0,8192),
// Vt[2] [8192,16384), P [16384,26624) per wave [32][40].
// ---------------------------------------------------------------------------
#define QT 256
#define KC 32

__global__ __launch_bounds__(512, 2) void flash_f16(
    const _Float16* __restrict__ Qg, const _Float16* __restrict__ Kg,
    const _Float16* __restrict__ Vtg, _Float16* __restrict__ Og) {
  __shared__ __align__(16) _Float16 sm[32768];

  const int t = threadIdx.x, w = t >> 6, lane = t & 63;   // w in 0..7
  const int quad = lane >> 4, c15 = lane & 15;
  // XCD swizzle: 32 blocks/XCD = 4 bh-groups x 8 q-chunks.
  const int bid = blockIdx.x;
  const int grp = (bid & 7) * 4 + ((bid >> 3) >> 3);   // 0..31 = b*NH+h
  const int qi  = (bid >> 3) & 7;
  const int bh = grp;
  const int hy = grp & (NH - 1), bz = grp >> 4;
  const int q0 = qi * QT;
  const int wr = w * 32;

  // ---- stage Q [256][128] f16 once; fragments -> registers ----
  {
    const _Float16* qsrc = Qg + ((size_t)bh * SEQ + q0) * HD;
    #pragma unroll
    for (int p = 0; p < 8; ++p) {
      int ci = p * 512 + t;
      int r = ci >> 4, c8 = (ci & 15) ^ (r & 15);
      __builtin_amdgcn_global_load_lds(
          (const __attribute__((address_space(1))) unsigned int*)(qsrc + (size_t)r * HD + c8 * 8),
          (__attribute__((address_space(3))) unsigned int*)(sm + ci * 8), 16, 0, 0);
    }
  }
  __syncthreads();
  f16x8 qf[2][4];  // [mf][ks]
  #pragma unroll
  for (int mf = 0; mf < 2; ++mf)
    #pragma unroll
    for (int ks = 0; ks < 4; ++ks) {
      int m = wr + mf * 16 + c15;
      int c8 = ks * 4 + quad;
      qf[mf][ks] = *(const f16x8*)(sm + (m * 16 + (c8 ^ (m & 15))) * 8);
    }
  // all waves' qf reads must retire before chunk staging overwrites [0,26624)
  asm volatile("s_waitcnt lgkmcnt(0)" ::: "memory");
  __builtin_amdgcn_sched_barrier(0);
  __syncthreads();

  float lrow[8];
  f32x4 oacc[2][8];
  #pragma unroll
  for (int i = 0; i < 8; ++i) lrow[i] = 0.f;
  #pragma unroll
  for (int mf = 0; mf < 2; ++mf)
    #pragma unroll
    for (int nf = 0; nf < 8; ++nf) oacc[mf][nf] = (f32x4){0.f, 0.f, 0.f, 0.f};

  const float sl = 0.12751744f;       // (1/sqrt(128)) * log2(e)
  const float M2 = 16.322231f;        // sqrt(128) * log2(e)
  _Float16* Pw = sm + 16384 + w * 1280;

  // 16 chunk loads (K 8, Vt 8) spread 2 per wave; tile wave-uniform.
  // K rows staged permuted: LDS row r <- global row kk + 2*(r&15)+(r>>4).
#define STAGE_KV(buf, kk)                                                     \
  _Pragma("unroll")                                                           \
  for (int e = 0; e < 2; ++e) {                                               \
    int idx = w * 2 + e;                                                      \
    int tile = idx >> 3, p = idx & 7;                                         \
    int ci = p * 64 + lane;                                                   \
    if (tile == 0) {                                                          \
      int r = ci >> 4, c8 = (ci & 15) ^ (r & 15);                             \
      int rp = 2 * (r & 15) + (r >> 4);                                       \
      const _Float16* src = Kg +                                              \
          ((size_t)bh * SEQ + (kk) + rp) * HD + c8 * 8;                       \
      __builtin_amdgcn_global_load_lds(                                       \
          (const __attribute__((address_space(1))) unsigned int*)src,         \
          (__attribute__((address_space(3))) unsigned int*)                   \
              (sm + (buf) * 4096 + ci * 8), 16, 0, 0);                        \
    } else {                                                                  \
      int d = ci >> 2, c8 = (ci & 3) ^ (d & 3);                               \
      const _Float16* src = Vtg + (size_t)bh * HD * SEQ + (size_t)d * SEQ     \
          + (kk) + c8 * 8;                                                    \
      __builtin_amdgcn_global_load_lds(                                       \
          (const __attribute__((address_space(1))) unsigned int*)src,         \
          (__attribute__((address_space(3))) unsigned int*)                   \
              (sm + 8192 + (buf) * 4096 + ci * 8), 16, 0, 0);                 \
    }                                                                         \
  }

  STAGE_KV(0, 0)                       // prologue: chunk 0 -> buf0

  const int NC = SEQ / KC;             // 64
  for (int it = 0; it < NC; ++it) {
    const int cur = it & 1, cb0 = cur * 4096;
    asm volatile("s_waitcnt vmcnt(0)" ::: "memory");
    __builtin_amdgcn_sched_barrier(0);
    __builtin_amdgcn_s_barrier();
    __builtin_amdgcn_sched_barrier(0);
    if (it + 1 < NC) { STAGE_KV(1 - cur, (it + 1) * KC) }

    // ---- S = Q K^T (single pass) ----
    f32x4 accs[2][2] = {};
    #pragma unroll
    for (int nf = 0; nf < 2; ++nf) {
      f16x8 kh[4];
      #pragma unroll
      for (int ks = 0; ks < 4; ++ks) {
        int n = nf * 16 + c15;
        int c8 = ks * 4 + quad;
        kh[ks] = *(const f16x8*)(sm + cb0 + (n * 16 + (c8 ^ (n & 15))) * 8);
      }
      __builtin_amdgcn_s_setprio(1);
      #pragma unroll
      for (int ks = 0; ks < 4; ++ks) {
        accs[0][nf] = MFMA_F16(qf[0][ks], kh[ks], accs[0][nf], 0, 0, 0);
        accs[1][nf] = MFMA_F16(qf[1][ks], kh[ks], accs[1][nf], 0, 0, 0);
      }
      __builtin_amdgcn_s_setprio(0);
    }

    // ---- fixed-shift softmax weights; packed f16x2 P-write ----
    // S fragment (nf,c15) = true kv 2*c15+nf (K row permutation), so p0,p1
    // are adjacent storage cols -> one b32 write (2-way bank = free).
    #pragma unroll
    for (int mf = 0; mf < 2; ++mf)
      #pragma unroll
      for (int reg = 0; reg < 4; ++reg) {
        float p0 = exp2f(fmaf(accs[mf][0][reg], sl, -M2));
        float p1 = exp2f(fmaf(accs[mf][1][reg], sl, -M2));
        lrow[mf * 4 + reg] += p0 + p1;
        int prow = mf * 16 + quad * 4 + reg;
        f16x2 pp;
        pp[0] = (_Float16)p0; pp[1] = (_Float16)p1;
        *(f16x2*)(Pw + prow * 40 + 2 * c15) = pp;
      }

    // ---- O += P V (kv index = storage col = identity for V) ----
    f16x8 pa0 = *(const f16x8*)(Pw + (c15) * 40 + quad * 8);
    f16x8 pa1 = *(const f16x8*)(Pw + (16 + c15) * 40 + quad * 8);
    __builtin_amdgcn_s_setprio(1);
    #pragma unroll
    for (int nf = 0; nf < 8; ++nf) {
      int dd = nf * 16 + c15;
      int slot = (dd * 4 + (quad ^ (dd & 3))) * 8;
      f16x8 vv = *(const f16x8*)(sm + 8192 + cb0 + slot);
      oacc[0][nf] = MFMA_F16(pa0, vv, oacc[0][nf], 0, 0, 0);
      oacc[1][nf] = MFMA_F16(pa1, vv, oacc[1][nf], 0, 0, 0);
    }
    __builtin_amdgcn_s_setprio(0);
  }

  // ---- epilogue: denominator reduce + O write (single fp16) ----
  #pragma unroll
  for (int i = 0; i < 8; ++i) {
    float s = lrow[i];
    #pragma unroll
    for (int off = 8; off >= 1; off >>= 1) s += __shfl_xor(s, off, 64);
    lrow[i] = s;
  }
  #pragma unroll
  for (int mf = 0; mf < 2; ++mf)
    #pragma unroll
    for (int reg = 0; reg < 4; ++reg) {
      float inv = 1.0f / lrow[mf * 4 + reg];
      int row = q0 + wr + mf * 16 + quad * 4 + reg;
      size_t ob = ((size_t)bz * SEQ + row) * DIM + hy * HD + c15;
      #pragma unroll
      for (int nf = 0; nf < 8; ++nf)
        Og[ob + nf * 16] = (_Float16)(oacc[mf][nf][reg] * inv);
    }
#undef STAGE_KV
}

// ---------------------------------------------------------------------------
// Launch (5 kernels, round-11 layout).  Workspace (<= 168 MB):
//   qkv16 (fp16) at ws[0, 50.3M); O16 reuses ws[0, 16.7M) after qkv consumed.
//   R = ws + 100663296:
//     x16 [R, +16.7M)  Wh [R+16.7M, +25.2M)  Wph [R+41.9M, +8.4M)
//     post-gemm1: Q16 [R)  K16 [R+16.7M)  Vt [R+50.3M, +16.7M)
// ---------------------------------------------------------------------------
extern "C" void kernel_launch(void* const* d_in, const int* in_sizes, int n_in,
                              void* d_out, int out_size, void* d_ws, size_t ws_size,
                              hipStream_t stream) {
  const float* x     = (const float*)d_in[0];
  const float* cosb  = (const float*)d_in[1];
  const float* sinb  = (const float*)d_in[2];
  const float* Wqkv  = (const float*)d_in[3];
  const float* Wproj = (const float*)d_in[4];
  float* out = (float*)d_out;

  char* ws = (char*)d_ws;
  _Float16* qkv16 = (_Float16*)ws;
  char* R = ws + 100663296;
  _Float16* x16 = (_Float16*)(R);
  _Float16* Wh  = (_Float16*)(R + 16777216);
  _Float16* Wph = (_Float16*)(R + 41943040);
  _Float16* Q16 = (_Float16*)(R);
  _Float16* K16 = (_Float16*)(R + 16777216);
  _Float16* Vt  = (_Float16*)(R + 50331648);
  _Float16* O16 = (_Float16*)(ws);

  cvt_all<<<24576, 256, 0, stream>>>(x, Wqkv, Wproj, x16, Wh, Wph);
  gemm_1p<_Float16><<<dim3(24, 32), 512, 0, stream>>>(x16, Wh, qkv16, 4096, 6144, 2048);
  rope_vtrans<<<5120, 256, 0, stream>>>(qkv16, cosb, sinb, Q16, K16, Vt);
  flash_f16<<<256, 512, 0, stream>>>(Q16, K16, Vt, O16);
  gemm_1p<float><<<dim3(8, 32), 512, 0, stream>>>(O16, Wph, out, 4096, 2048, 2048);
}